// Round 2
// baseline (11528.807 us; speedup 1.0000x reference)
//
#include <hip/hip_runtime.h>
#include <hip/hip_bf16.h>

#define CIN 32
#define COUT 32
#define LRELU_SLOPE 0.01f
#define BN_EPS 1e-5f
#define CHUNK 2048

__device__ __forceinline__ float4 lrelu4(float4 v) {
    float4 a;
    a.x = v.x >= 0.f ? v.x : LRELU_SLOPE * v.x;
    a.y = v.y >= 0.f ? v.y : LRELU_SLOPE * v.y;
    a.z = v.z >= 0.f ? v.z : LRELU_SLOPE * v.z;
    a.w = v.w >= 0.f ? v.w : LRELU_SLOPE * v.w;
    return a;
}

__device__ __forceinline__ unsigned f2bf(float f) {
    unsigned u = __float_as_uint(f);
    return (u + 0x7fffu + ((u >> 16) & 1u)) >> 16;   // RNE, NaN-free data
}

// ---------------- fast path: CSR build ----------------

__global__ void __launch_bounds__(256) hist_kernel(
    const int* __restrict__ po, int* __restrict__ cnt, int E)
{
    int i = blockIdx.x * blockDim.x + threadIdx.x;
    if (i < E) atomicAdd(&cnt[po[i]], 1);
}

__global__ void __launch_bounds__(256) blocksum_kernel(
    const int* __restrict__ cnt, int* __restrict__ bsum, int N)
{
    int base = blockIdx.x * CHUNK + threadIdx.x * 8;
    int s = 0;
#pragma unroll
    for (int j = 0; j < 8; ++j) { int i = base + j; if (i < N) s += cnt[i]; }
#pragma unroll
    for (int off = 1; off < 64; off <<= 1) s += __shfl_xor(s, off);
    __shared__ int wsum[4];
    if ((threadIdx.x & 63) == 0) wsum[threadIdx.x >> 6] = s;
    __syncthreads();
    if (threadIdx.x == 0) bsum[blockIdx.x] = wsum[0] + wsum[1] + wsum[2] + wsum[3];
}

__global__ void scanblk_kernel(const int* __restrict__ bsum, int* __restrict__ boffs, int nb)
{
    int run = 0;
    for (int b = 0; b < nb; ++b) { boffs[b] = run; run += bsum[b]; }
}

// in-place: cnt -> exclusive offsets; also copy into cursors
__global__ void __launch_bounds__(256) scatteroffs_kernel(
    int* __restrict__ cnt, int* __restrict__ cursors,
    const int* __restrict__ boffs, int N)
{
    int tid = threadIdx.x;
    int base = blockIdx.x * CHUNK + tid * 8;
    int c[8]; int tsum = 0;
#pragma unroll
    for (int j = 0; j < 8; ++j) { int i = base + j; c[j] = (i < N) ? cnt[i] : 0; tsum += c[j]; }
    __shared__ int lts[256];
    lts[tid] = tsum;
    __syncthreads();
    int off = boffs[blockIdx.x];
    for (int j = 0; j < tid; ++j) off += lts[j];
#pragma unroll
    for (int j = 0; j < 8; ++j) {
        int i = base + j;
        if (i < N) { cnt[i] = off; cursors[i] = off; off += c[j]; }
    }
}

// ---------------- fast path: conv + slot scatter ----------------

__global__ void __launch_bounds__(256) conv_fill_kernel(
    const float* __restrict__ features,
    const float* __restrict__ weight,
    const int* __restrict__ pairs_in,
    const int* __restrict__ pairs_out,
    int* __restrict__ cursors,
    uint4* __restrict__ entry,          // E rows of 64B (32 bf16)
    int P)
{
    int p = blockIdx.x * blockDim.x + threadIdx.x;
    int k = blockIdx.y;                 // wave-uniform -> scalar W loads
    if (p >= P) return;

    int pi = pairs_in[(size_t)k * P + p];
    int po = pairs_out[(size_t)k * P + p];

    const float4* __restrict__ frow = (const float4*)(features + (size_t)pi * CIN);
    const float* __restrict__ wk = weight + (size_t)k * CIN * COUT;

    float acc[COUT];
#pragma unroll
    for (int co = 0; co < COUT; ++co) acc[co] = 0.f;

#pragma unroll
    for (int c4 = 0; c4 < CIN / 4; ++c4) {
        float4 f = frow[c4];
        float fv[4] = {f.x, f.y, f.z, f.w};
#pragma unroll
        for (int j = 0; j < 4; ++j) {
            const float* __restrict__ wr = wk + (c4 * 4 + j) * COUT;
#pragma unroll
            for (int co = 0; co < COUT; ++co)
                acc[co] = fmaf(fv[j], wr[co], acc[co]);
        }
    }

    int slot = atomicAdd(&cursors[po], 1);

    uint4 pk[4];
    unsigned* pu = (unsigned*)pk;
#pragma unroll
    for (int i = 0; i < 16; ++i)
        pu[i] = f2bf(acc[2 * i]) | (f2bf(acc[2 * i + 1]) << 16);

    uint4* __restrict__ dst = entry + (size_t)slot * 4;
    dst[0] = pk[0]; dst[1] = pk[1]; dst[2] = pk[2]; dst[3] = pk[3];
}

// ---------------- fast path: contiguous reduce + lrelu + stats ----------------

__global__ void __launch_bounds__(256) reduce_kernel(
    const uint2* __restrict__ entry,
    const int* __restrict__ offsets,
    float* __restrict__ out,
    float* __restrict__ stats,          // [0..31] sum, [32..63] sumsq
    int N, int E)
{
    int gid = blockIdx.x * 256 + threadIdx.x;
    int r = gid >> 3;
    int t = gid & 7;                    // channel quad

    float4 act = {0.f, 0.f, 0.f, 0.f};
    if (r < N) {
        int beg = offsets[r];
        int end = (r == N - 1) ? E : offsets[r + 1];
        float4 a = {0.f, 0.f, 0.f, 0.f};
        for (int e = beg; e < end; ++e) {
            uint2 w = entry[(size_t)e * 8 + t];
            a.x += __uint_as_float(w.x << 16);
            a.y += __uint_as_float(w.x & 0xffff0000u);
            a.z += __uint_as_float(w.y << 16);
            a.w += __uint_as_float(w.y & 0xffff0000u);
        }
        act = lrelu4(a);
        ((float4*)out)[gid] = act;
    }

    float4 s = act;
    float4 q = {act.x * act.x, act.y * act.y, act.z * act.z, act.w * act.w};
#pragma unroll
    for (int off = 8; off < 64; off <<= 1) {
        s.x += __shfl_xor(s.x, off); s.y += __shfl_xor(s.y, off);
        s.z += __shfl_xor(s.z, off); s.w += __shfl_xor(s.w, off);
        q.x += __shfl_xor(q.x, off); q.y += __shfl_xor(q.y, off);
        q.z += __shfl_xor(q.z, off); q.w += __shfl_xor(q.w, off);
    }
    __shared__ float4 rs[4][8];
    __shared__ float4 rq[4][8];
    int lane = threadIdx.x & 63;
    int w = threadIdx.x >> 6;
    if (lane < 8) { rs[w][lane] = s; rq[w][lane] = q; }
    __syncthreads();
    if (threadIdx.x < 8) {
        int qd = threadIdx.x;
        float4 S = {0.f, 0.f, 0.f, 0.f};
        float4 Q = {0.f, 0.f, 0.f, 0.f};
        for (int ww = 0; ww < 4; ++ww) {
            float4 a = rs[ww][qd], b = rq[ww][qd];
            S.x += a.x; S.y += a.y; S.z += a.z; S.w += a.w;
            Q.x += b.x; Q.y += b.y; Q.z += b.z; Q.w += b.w;
        }
        atomicAdd(&stats[qd * 4 + 0], S.x); atomicAdd(&stats[qd * 4 + 1], S.y);
        atomicAdd(&stats[qd * 4 + 2], S.z); atomicAdd(&stats[qd * 4 + 3], S.w);
        atomicAdd(&stats[32 + qd * 4 + 0], Q.x); atomicAdd(&stats[32 + qd * 4 + 1], Q.y);
        atomicAdd(&stats[32 + qd * 4 + 2], Q.z); atomicAdd(&stats[32 + qd * 4 + 3], Q.w);
    }
}

// norm WITHOUT re-applying lrelu (input already activated)
__global__ void __launch_bounds__(256) norm2_kernel(
    float* __restrict__ data, const float* __restrict__ stats,
    const float* __restrict__ gamma, const float* __restrict__ beta,
    int n4, float invN)
{
    int i = blockIdx.x * blockDim.x + threadIdx.x;
    if (i >= n4) return;
    int qd = i & 7;
    float sc[4], bs[4];
#pragma unroll
    for (int j = 0; j < 4; ++j) {
        int c = qd * 4 + j;
        float m = stats[c] * invN;
        float v = stats[32 + c] * invN - m * m;
        float inv = rsqrtf(v + BN_EPS);
        sc[j] = inv * gamma[c];
        bs[j] = beta[c] - m * sc[j];
    }
    float4* d4 = (float4*)data;
    float4 a = d4[i];
    float4 y;
    y.x = a.x * sc[0] + bs[0];
    y.y = a.y * sc[1] + bs[1];
    y.z = a.z * sc[2] + bs[2];
    y.w = a.w * sc[3] + bs[3];
    d4[i] = y;
}

// ---------------- fallback path (round-1 atomic version) ----------------

__global__ void __launch_bounds__(256) conv_atomic_kernel(
    const float* __restrict__ features,
    const float* __restrict__ weight,
    const int* __restrict__ pairs_in,
    const int* __restrict__ pairs_out,
    float* __restrict__ out,
    int P)
{
    int p = blockIdx.x * blockDim.x + threadIdx.x;
    int k = blockIdx.y;
    if (p >= P) return;
    int pi = pairs_in[(size_t)k * P + p];
    int po = pairs_out[(size_t)k * P + p];
    const float4* __restrict__ frow = (const float4*)(features + (size_t)pi * CIN);
    const float* __restrict__ wk = weight + (size_t)k * CIN * COUT;
    float acc[COUT];
#pragma unroll
    for (int co = 0; co < COUT; ++co) acc[co] = 0.f;
#pragma unroll
    for (int c4 = 0; c4 < CIN / 4; ++c4) {
        float4 f = frow[c4];
        float fv[4] = {f.x, f.y, f.z, f.w};
#pragma unroll
        for (int j = 0; j < 4; ++j) {
            const float* __restrict__ wr = wk + (c4 * 4 + j) * COUT;
#pragma unroll
            for (int co = 0; co < COUT; ++co)
                acc[co] = fmaf(fv[j], wr[co], acc[co]);
        }
    }
    float* orow = out + (size_t)po * COUT;
#pragma unroll
    for (int co = 0; co < COUT; ++co)
        atomicAdd(orow + co, acc[co]);
}

__global__ void __launch_bounds__(256) stats_fb_kernel(
    const float* __restrict__ conv, float* __restrict__ stats, int n4)
{
    const float4* __restrict__ c4p = (const float4*)conv;
    int stride = blockDim.x * gridDim.x;
    float4 s = {0.f, 0.f, 0.f, 0.f};
    float4 q = {0.f, 0.f, 0.f, 0.f};
    for (int i = blockIdx.x * blockDim.x + threadIdx.x; i < n4; i += stride) {
        float4 a = lrelu4(c4p[i]);
        s.x += a.x; s.y += a.y; s.z += a.z; s.w += a.w;
        q.x += a.x * a.x; q.y += a.y * a.y; q.z += a.z * a.z; q.w += a.w * a.w;
    }
#pragma unroll
    for (int off = 8; off < 64; off <<= 1) {
        s.x += __shfl_xor(s.x, off); s.y += __shfl_xor(s.y, off);
        s.z += __shfl_xor(s.z, off); s.w += __shfl_xor(s.w, off);
        q.x += __shfl_xor(q.x, off); q.y += __shfl_xor(q.y, off);
        q.z += __shfl_xor(q.z, off); q.w += __shfl_xor(q.w, off);
    }
    __shared__ float4 rs[4][8];
    __shared__ float4 rq[4][8];
    int lane = threadIdx.x & 63;
    int w = threadIdx.x >> 6;
    if (lane < 8) { rs[w][lane] = s; rq[w][lane] = q; }
    __syncthreads();
    if (threadIdx.x < 8) {
        int qd = threadIdx.x;
        float4 S = {0.f, 0.f, 0.f, 0.f};
        float4 Q = {0.f, 0.f, 0.f, 0.f};
        for (int ww = 0; ww < 4; ++ww) {
            float4 a = rs[ww][qd], b = rq[ww][qd];
            S.x += a.x; S.y += a.y; S.z += a.z; S.w += a.w;
            Q.x += b.x; Q.y += b.y; Q.z += b.z; Q.w += b.w;
        }
        atomicAdd(&stats[qd * 4 + 0], S.x); atomicAdd(&stats[qd * 4 + 1], S.y);
        atomicAdd(&stats[qd * 4 + 2], S.z); atomicAdd(&stats[qd * 4 + 3], S.w);
        atomicAdd(&stats[32 + qd * 4 + 0], Q.x); atomicAdd(&stats[32 + qd * 4 + 1], Q.y);
        atomicAdd(&stats[32 + qd * 4 + 2], Q.z); atomicAdd(&stats[32 + qd * 4 + 3], Q.w);
    }
}

__global__ void __launch_bounds__(256) norm_fb_kernel(
    float* __restrict__ data, const float* __restrict__ stats,
    const float* __restrict__ gamma, const float* __restrict__ beta,
    int n4, float invN)
{
    int i = blockIdx.x * blockDim.x + threadIdx.x;
    if (i >= n4) return;
    int qd = i & 7;
    float sc[4], bs[4];
#pragma unroll
    for (int j = 0; j < 4; ++j) {
        int c = qd * 4 + j;
        float m = stats[c] * invN;
        float v = stats[32 + c] * invN - m * m;
        float inv = rsqrtf(v + BN_EPS);
        sc[j] = inv * gamma[c];
        bs[j] = beta[c] - m * sc[j];
    }
    float4* d4 = (float4*)data;
    float4 a = lrelu4(d4[i]);
    float4 y;
    y.x = a.x * sc[0] + bs[0];
    y.y = a.y * sc[1] + bs[1];
    y.z = a.z * sc[2] + bs[2];
    y.w = a.w * sc[3] + bs[3];
    d4[i] = y;
}

extern "C" void kernel_launch(void* const* d_in, const int* in_sizes, int n_in,
                              void* d_out, int out_size, void* d_ws, size_t ws_size,
                              hipStream_t stream) {
    const float* features = (const float*)d_in[0];
    const float* weight   = (const float*)d_in[1];
    const float* gamma    = (const float*)d_in[2];
    const float* beta     = (const float*)d_in[3];
    const int* pairs_in   = (const int*)d_in[4];
    const int* pairs_out  = (const int*)d_in[5];
    float* out = (float*)d_out;

    int N  = in_sizes[0] / CIN;           // 500000
    int KW = in_sizes[1] / (CIN * COUT);  // 27
    int P  = in_sizes[4] / KW;            // 250000
    int E  = KW * P;                      // 6,750,000
    int n4 = N * (COUT / 4);

    // ws layout (fast path)
    char* wsb = (char*)d_ws;
    float* stats  = (float*)wsb;                        // 64 floats
    int* offsets  = (int*)(wsb + 256);                  // N ints (counts -> offsets)
    int* cursors  = offsets + N;                        // N ints
    int* bsum     = cursors + N;                        // <=1024 ints
    int* boffs    = bsum + 1024;                        // <=1024 ints
    size_t entryOff = ((size_t)(256 + 2 * (size_t)N * 4 + 8192) + 255) & ~(size_t)255;
    uint4* entry  = (uint4*)(wsb + entryOff);           // E * 64B
    size_t need = entryOff + (size_t)E * 64;

    if (ws_size >= need) {
        hipMemsetAsync(stats, 0, 256, stream);
        hipMemsetAsync(offsets, 0, (size_t)N * sizeof(int), stream);

        hist_kernel<<<(E + 255) / 256, 256, 0, stream>>>(pairs_out, offsets, E);

        int nb = (N + CHUNK - 1) / CHUNK;
        blocksum_kernel<<<nb, 256, 0, stream>>>(offsets, bsum, N);
        scanblk_kernel<<<1, 1, 0, stream>>>(bsum, boffs, nb);
        scatteroffs_kernel<<<nb, 256, 0, stream>>>(offsets, cursors, boffs, N);

        dim3 cgrid((P + 255) / 256, KW);
        conv_fill_kernel<<<cgrid, 256, 0, stream>>>(features, weight, pairs_in,
                                                    pairs_out, cursors, entry, P);

        reduce_kernel<<<(N * 8 + 255) / 256, 256, 0, stream>>>(
            (const uint2*)entry, offsets, out, stats, N, E);

        norm2_kernel<<<(n4 + 255) / 256, 256, 0, stream>>>(out, stats, gamma, beta,
                                                           n4, 1.0f / (float)N);
    } else {
        // fallback: atomic scatter version
        hipMemsetAsync(d_out, 0, (size_t)out_size * sizeof(float), stream);
        hipMemsetAsync(d_ws, 0, 64 * sizeof(float), stream);
        dim3 cgrid((P + 255) / 256, KW);
        conv_atomic_kernel<<<cgrid, 256, 0, stream>>>(features, weight, pairs_in,
                                                      pairs_out, (float*)d_out, P);
        stats_fb_kernel<<<512, 256, 0, stream>>>((const float*)d_out, (float*)d_ws, n4);
        norm_fb_kernel<<<(n4 + 255) / 256, 256, 0, stream>>>((float*)d_out, (float*)d_ws,
                                                             gamma, beta, n4,
                                                             1.0f / (float)N);
    }
}

// Round 3
// 1738.751 us; speedup vs baseline: 6.6305x; 6.6305x over previous
//
#include <hip/hip_runtime.h>
#include <hip/hip_fp16.h>

#define CIN 32
#define COUT 32
#define LRELU_SLOPE 0.01f
#define BN_EPS 1e-5f
#define CHUNK 2048
#define KMAX 27
#define PBITS 18
#define PMASK 0x3FFFF

// ---------------- CSR build ----------------

__global__ void __launch_bounds__(256) hist_kernel(
    const int* __restrict__ po, int* __restrict__ cnt, int E)
{
    int i = blockIdx.x * blockDim.x + threadIdx.x;
    if (i < E) atomicAdd(&cnt[po[i]], 1);
}

__global__ void __launch_bounds__(256) blocksum_kernel(
    const int* __restrict__ cnt, int* __restrict__ bsum, int N)
{
    int base = blockIdx.x * CHUNK + threadIdx.x * 8;
    int s = 0;
#pragma unroll
    for (int j = 0; j < 8; ++j) { int i = base + j; if (i < N) s += cnt[i]; }
#pragma unroll
    for (int off = 1; off < 64; off <<= 1) s += __shfl_xor(s, off);
    __shared__ int wsum[4];
    if ((threadIdx.x & 63) == 0) wsum[threadIdx.x >> 6] = s;
    __syncthreads();
    if (threadIdx.x == 0) bsum[blockIdx.x] = wsum[0] + wsum[1] + wsum[2] + wsum[3];
}

__global__ void scanblk_kernel(const int* __restrict__ bsum, int* __restrict__ boffs, int nb)
{
    int run = 0;
    for (int b = 0; b < nb; ++b) { boffs[b] = run; run += bsum[b]; }
}

__global__ void __launch_bounds__(256) scatteroffs_kernel(
    int* __restrict__ cnt, int* __restrict__ cursors,
    const int* __restrict__ boffs, int N)
{
    int tid = threadIdx.x;
    int base = blockIdx.x * CHUNK + tid * 8;
    int c[8]; int tsum = 0;
#pragma unroll
    for (int j = 0; j < 8; ++j) { int i = base + j; c[j] = (i < N) ? cnt[i] : 0; tsum += c[j]; }
    __shared__ int lts[256];
    lts[tid] = tsum;
    __syncthreads();
    int off = boffs[blockIdx.x];
    for (int j = 0; j < tid; ++j) off += lts[j];
#pragma unroll
    for (int j = 0; j < 8; ++j) {
        int i = base + j;
        if (i < N) { cnt[i] = off; cursors[i] = off; off += c[j]; }
    }
}

__global__ void __launch_bounds__(256) scatter_kernel(
    const int* __restrict__ pairs_out, int* __restrict__ cursors,
    int* __restrict__ sorted, int P)
{
    int p = blockIdx.x * blockDim.x + threadIdx.x;
    int k = blockIdx.y;
    if (p >= P) return;
    int po = pairs_out[(size_t)k * P + p];
    int slot = atomicAdd(&cursors[po], 1);
    sorted[slot] = (k << PBITS) | p;
}

// ---------------- fused conv + lrelu + stats ----------------
// thread = one output row; W (27x32x32) in LDS as f16, layout [c][co8][k] 16B chunks

__global__ void __launch_bounds__(256, 2) fused_conv_kernel(
    const float* __restrict__ features,
    const float* __restrict__ weight,
    const int* __restrict__ pairs_in,
    const int* __restrict__ sorted,
    const int* __restrict__ offsets,
    float* __restrict__ out,
    float* __restrict__ gstats,         // [0..31] sum, [32..63] sumsq
    int N, int E, int P)
{
    __shared__ uint4 wlds[32 * 4 * KMAX];        // 3456 chunks = 55,296 B
    __shared__ float sred[4][32];
    __shared__ float qred[4][32];

    // stage W: global fp32 [k][c][co] -> LDS f16 chunk[(c*4+co>>3)*27+k][co&7]
    {
        __half* hl = (__half*)wlds;
        for (int s = threadIdx.x; s < KMAX * 1024; s += 256) {
            int k = s >> 10;
            int rem = s & 1023;
            int c = rem >> 5;
            int co = rem & 31;
            float v = weight[s];
            int dst = (((c << 2) + (co >> 3)) * KMAX + k) * 8 + (co & 7);
            hl[dst] = __float2half(v);
        }
    }
    __syncthreads();

    int r = blockIdx.x * 256 + threadIdx.x;

    float acc[COUT];
#pragma unroll
    for (int co = 0; co < COUT; ++co) acc[co] = 0.f;

    if (r < N) {
        int beg = offsets[r];
        int end = (r == N - 1) ? E : offsets[r + 1];
        int cnt = end - beg;
        if (cnt > 0) {
            // 3-stage pipeline over the sorted->pairs_in->features chain
            int pk0 = sorted[beg];
            int pk1 = (cnt > 1) ? sorted[beg + 1] : pk0;
            int pk2 = (cnt > 2) ? sorted[beg + 2] : pk1;
            int pi0 = pairs_in[(pk0 >> PBITS) * P + (pk0 & PMASK)];
            int pi1 = pairs_in[(pk1 >> PBITS) * P + (pk1 & PMASK)];
            float4 fc[8];
            {
                const float4* fr = (const float4*)(features + (size_t)pi0 * CIN);
#pragma unroll
                for (int i = 0; i < 8; ++i) fc[i] = fr[i];
            }
            for (int e = 0; e < cnt; ++e) {
                // issue next feature row load
                float4 fn[8];
                {
                    const float4* fr = (const float4*)(features + (size_t)pi1 * CIN);
#pragma unroll
                    for (int i = 0; i < 8; ++i) fn[i] = fr[i];
                }
                // prefetch sorted for e+3
                int pk3 = (beg + e + 3 < end) ? sorted[beg + e + 3] : pk2;
                // resolve pairs_in for e+2 (pk2 already landed)
                int pi2 = pairs_in[(pk2 >> PBITS) * P + (pk2 & PMASK)];

                int k = pk0 >> PBITS;
#pragma unroll
                for (int c4 = 0; c4 < 8; ++c4) {
                    float4 fq = fc[c4];
                    float fv[4] = {fq.x, fq.y, fq.z, fq.w};
#pragma unroll
                    for (int j = 0; j < 4; ++j) {
                        int c = c4 * 4 + j;
                        float f = fv[j];
#pragma unroll
                        for (int co8 = 0; co8 < 4; ++co8) {
                            uint4 w = wlds[((c << 2) + co8) * KMAX + k];
                            const __half2* h2 = reinterpret_cast<const __half2*>(&w);
                            int b = co8 * 8;
                            acc[b + 0] = fmaf(f, __low2float(h2[0]),  acc[b + 0]);
                            acc[b + 1] = fmaf(f, __high2float(h2[0]), acc[b + 1]);
                            acc[b + 2] = fmaf(f, __low2float(h2[1]),  acc[b + 2]);
                            acc[b + 3] = fmaf(f, __high2float(h2[1]), acc[b + 3]);
                            acc[b + 4] = fmaf(f, __low2float(h2[2]),  acc[b + 4]);
                            acc[b + 5] = fmaf(f, __high2float(h2[2]), acc[b + 5]);
                            acc[b + 6] = fmaf(f, __low2float(h2[3]),  acc[b + 6]);
                            acc[b + 7] = fmaf(f, __high2float(h2[3]), acc[b + 7]);
                        }
                    }
                }
                // rotate pipeline
                pk0 = pk1; pk1 = pk2; pk2 = pk3;
                pi0 = pi1; pi1 = pi2;
#pragma unroll
                for (int i = 0; i < 8; ++i) fc[i] = fn[i];
            }
        }
    }

    // LeakyReLU + store
    float act[COUT];
#pragma unroll
    for (int co = 0; co < COUT; ++co) {
        float a = acc[co];
        act[co] = a >= 0.f ? a : LRELU_SLOPE * a;
    }
    if (r < N) {
        float4* orow = (float4*)(out + (size_t)r * COUT);
#pragma unroll
        for (int i = 0; i < 8; ++i)
            orow[i] = make_float4(act[i * 4], act[i * 4 + 1], act[i * 4 + 2], act[i * 4 + 3]);
    }

    // stats: wave shfl-reduce, then block LDS, then 64 atomics
    float q[COUT];
#pragma unroll
    for (int co = 0; co < COUT; ++co) q[co] = act[co] * act[co];
#pragma unroll
    for (int off = 1; off < 64; off <<= 1) {
#pragma unroll
        for (int co = 0; co < COUT; ++co) {
            act[co] += __shfl_xor(act[co], off);
            q[co]   += __shfl_xor(q[co], off);
        }
    }
    int lane = threadIdx.x & 63;
    int wv = threadIdx.x >> 6;
    if (lane == 0) {
#pragma unroll
        for (int co = 0; co < COUT; ++co) { sred[wv][co] = act[co]; qred[wv][co] = q[co]; }
    }
    __syncthreads();
    if (threadIdx.x < 32) {
        int c = threadIdx.x;
        float S = sred[0][c] + sred[1][c] + sred[2][c] + sred[3][c];
        float Q = qred[0][c] + qred[1][c] + qred[2][c] + qred[3][c];
        atomicAdd(&gstats[c], S);
        atomicAdd(&gstats[32 + c], Q);
    }
}

// norm WITHOUT re-applying lrelu (input already activated)
__global__ void __launch_bounds__(256) norm2_kernel(
    float* __restrict__ data, const float* __restrict__ stats,
    const float* __restrict__ gamma, const float* __restrict__ beta,
    int n4, float invN)
{
    int i = blockIdx.x * blockDim.x + threadIdx.x;
    if (i >= n4) return;
    int qd = i & 7;
    float sc[4], bs[4];
#pragma unroll
    for (int j = 0; j < 4; ++j) {
        int c = qd * 4 + j;
        float m = stats[c] * invN;
        float v = stats[32 + c] * invN - m * m;
        float inv = rsqrtf(v + BN_EPS);
        sc[j] = inv * gamma[c];
        bs[j] = beta[c] - m * sc[j];
    }
    float4* d4 = (float4*)data;
    float4 a = d4[i];
    float4 y;
    y.x = a.x * sc[0] + bs[0];
    y.y = a.y * sc[1] + bs[1];
    y.z = a.z * sc[2] + bs[2];
    y.w = a.w * sc[3] + bs[3];
    d4[i] = y;
}

// ---------------- fallback path (atomic version) ----------------

__global__ void __launch_bounds__(256) conv_atomic_kernel(
    const float* __restrict__ features,
    const float* __restrict__ weight,
    const int* __restrict__ pairs_in,
    const int* __restrict__ pairs_out,
    float* __restrict__ out,
    int P)
{
    int p = blockIdx.x * blockDim.x + threadIdx.x;
    int k = blockIdx.y;
    if (p >= P) return;
    int pi = pairs_in[(size_t)k * P + p];
    int po = pairs_out[(size_t)k * P + p];
    const float4* __restrict__ frow = (const float4*)(features + (size_t)pi * CIN);
    const float* __restrict__ wk = weight + (size_t)k * CIN * COUT;
    float acc[COUT];
#pragma unroll
    for (int co = 0; co < COUT; ++co) acc[co] = 0.f;
#pragma unroll
    for (int c4 = 0; c4 < CIN / 4; ++c4) {
        float4 f = frow[c4];
        float fv[4] = {f.x, f.y, f.z, f.w};
#pragma unroll
        for (int j = 0; j < 4; ++j) {
            const float* __restrict__ wr = wk + (c4 * 4 + j) * COUT;
#pragma unroll
            for (int co = 0; co < COUT; ++co)
                acc[co] = fmaf(fv[j], wr[co], acc[co]);
        }
    }
    float* orow = out + (size_t)po * COUT;
#pragma unroll
    for (int co = 0; co < COUT; ++co)
        atomicAdd(orow + co, acc[co]);
}

__device__ __forceinline__ float4 lrelu4(float4 v) {
    float4 a;
    a.x = v.x >= 0.f ? v.x : LRELU_SLOPE * v.x;
    a.y = v.y >= 0.f ? v.y : LRELU_SLOPE * v.y;
    a.z = v.z >= 0.f ? v.z : LRELU_SLOPE * v.z;
    a.w = v.w >= 0.f ? v.w : LRELU_SLOPE * v.w;
    return a;
}

__global__ void __launch_bounds__(256) stats_fb_kernel(
    const float* __restrict__ conv, float* __restrict__ stats, int n4)
{
    const float4* __restrict__ c4p = (const float4*)conv;
    int stride = blockDim.x * gridDim.x;
    float4 s = {0.f, 0.f, 0.f, 0.f};
    float4 q = {0.f, 0.f, 0.f, 0.f};
    for (int i = blockIdx.x * blockDim.x + threadIdx.x; i < n4; i += stride) {
        float4 a = lrelu4(c4p[i]);
        s.x += a.x; s.y += a.y; s.z += a.z; s.w += a.w;
        q.x += a.x * a.x; q.y += a.y * a.y; q.z += a.z * a.z; q.w += a.w * a.w;
    }
#pragma unroll
    for (int off = 8; off < 64; off <<= 1) {
        s.x += __shfl_xor(s.x, off); s.y += __shfl_xor(s.y, off);
        s.z += __shfl_xor(s.z, off); s.w += __shfl_xor(s.w, off);
        q.x += __shfl_xor(q.x, off); q.y += __shfl_xor(q.y, off);
        q.z += __shfl_xor(q.z, off); q.w += __shfl_xor(q.w, off);
    }
    __shared__ float4 rs[4][8];
    __shared__ float4 rq[4][8];
    int lane = threadIdx.x & 63;
    int w = threadIdx.x >> 6;
    if (lane < 8) { rs[w][lane] = s; rq[w][lane] = q; }
    __syncthreads();
    if (threadIdx.x < 8) {
        int qd = threadIdx.x;
        float4 S = {0.f, 0.f, 0.f, 0.f};
        float4 Q = {0.f, 0.f, 0.f, 0.f};
        for (int ww = 0; ww < 4; ++ww) {
            float4 a = rs[ww][qd], b = rq[ww][qd];
            S.x += a.x; S.y += a.y; S.z += a.z; S.w += a.w;
            Q.x += b.x; Q.y += b.y; Q.z += b.z; Q.w += b.w;
        }
        atomicAdd(&stats[qd * 4 + 0], S.x); atomicAdd(&stats[qd * 4 + 1], S.y);
        atomicAdd(&stats[qd * 4 + 2], S.z); atomicAdd(&stats[qd * 4 + 3], S.w);
        atomicAdd(&stats[32 + qd * 4 + 0], Q.x); atomicAdd(&stats[32 + qd * 4 + 1], Q.y);
        atomicAdd(&stats[32 + qd * 4 + 2], Q.z); atomicAdd(&stats[32 + qd * 4 + 3], Q.w);
    }
}

__global__ void __launch_bounds__(256) norm_fb_kernel(
    float* __restrict__ data, const float* __restrict__ stats,
    const float* __restrict__ gamma, const float* __restrict__ beta,
    int n4, float invN)
{
    int i = blockIdx.x * blockDim.x + threadIdx.x;
    if (i >= n4) return;
    int qd = i & 7;
    float sc[4], bs[4];
#pragma unroll
    for (int j = 0; j < 4; ++j) {
        int c = qd * 4 + j;
        float m = stats[c] * invN;
        float v = stats[32 + c] * invN - m * m;
        float inv = rsqrtf(v + BN_EPS);
        sc[j] = inv * gamma[c];
        bs[j] = beta[c] - m * sc[j];
    }
    float4* d4 = (float4*)data;
    float4 a = lrelu4(d4[i]);
    float4 y;
    y.x = a.x * sc[0] + bs[0];
    y.y = a.y * sc[1] + bs[1];
    y.z = a.z * sc[2] + bs[2];
    y.w = a.w * sc[3] + bs[3];
    d4[i] = y;
}

extern "C" void kernel_launch(void* const* d_in, const int* in_sizes, int n_in,
                              void* d_out, int out_size, void* d_ws, size_t ws_size,
                              hipStream_t stream) {
    const float* features = (const float*)d_in[0];
    const float* weight   = (const float*)d_in[1];
    const float* gamma    = (const float*)d_in[2];
    const float* beta     = (const float*)d_in[3];
    const int* pairs_in   = (const int*)d_in[4];
    const int* pairs_out  = (const int*)d_in[5];
    float* out = (float*)d_out;

    int N  = in_sizes[0] / CIN;           // 500000
    int KW = in_sizes[1] / (CIN * COUT);  // 27
    int P  = in_sizes[4] / KW;            // 250000
    int E  = KW * P;                      // 6,750,000
    int n4 = N * (COUT / 4);

    // ws layout (fast path): stats | offsets[N] | cursors[N] | bsum | boffs | sorted[E]
    char* wsb = (char*)d_ws;
    float* stats  = (float*)wsb;                          // 64 floats (256 B slot)
    int* offsets  = (int*)(wsb + 256);
    int* cursors  = offsets + N;
    int* bsum     = cursors + N;
    int* boffs    = bsum + 1024;
    int* sorted   = boffs + 1024;
    size_t need = 256 + (size_t)(2 * N + 2048 + E) * 4;

    bool fast = (ws_size >= need) && (KW <= KMAX) && (P <= (1 << PBITS));

    if (fast) {
        hipMemsetAsync(stats, 0, 256, stream);
        hipMemsetAsync(offsets, 0, (size_t)N * sizeof(int), stream);

        hist_kernel<<<(E + 255) / 256, 256, 0, stream>>>(pairs_out, offsets, E);

        int nb = (N + CHUNK - 1) / CHUNK;
        blocksum_kernel<<<nb, 256, 0, stream>>>(offsets, bsum, N);
        scanblk_kernel<<<1, 1, 0, stream>>>(bsum, boffs, nb);
        scatteroffs_kernel<<<nb, 256, 0, stream>>>(offsets, cursors, boffs, N);

        dim3 sgrid((P + 255) / 256, KW);
        scatter_kernel<<<sgrid, 256, 0, stream>>>(pairs_out, cursors, sorted, P);

        fused_conv_kernel<<<(N + 255) / 256, 256, 0, stream>>>(
            features, weight, pairs_in, sorted, offsets, out, stats, N, E, P);

        norm2_kernel<<<(n4 + 255) / 256, 256, 0, stream>>>(out, stats, gamma, beta,
                                                           n4, 1.0f / (float)N);
    } else {
        hipMemsetAsync(d_out, 0, (size_t)out_size * sizeof(float), stream);
        hipMemsetAsync(d_ws, 0, 64 * sizeof(float), stream);
        dim3 cgrid((P + 255) / 256, KW);
        conv_atomic_kernel<<<cgrid, 256, 0, stream>>>(features, weight, pairs_in,
                                                      pairs_out, (float*)d_out, P);
        stats_fb_kernel<<<512, 256, 0, stream>>>((const float*)d_out, (float*)d_ws, n4);
        norm_fb_kernel<<<(n4 + 255) / 256, 256, 0, stream>>>((float*)d_out, (float*)d_ws,
                                                             gamma, beta, n4,
                                                             1.0f / (float)N);
    }
}

// Round 4
// 1371.910 us; speedup vs baseline: 8.4035x; 1.2674x over previous
//
#include <hip/hip_runtime.h>
#include <hip/hip_fp16.h>

#define CIN 32
#define COUT 32
#define LRELU_SLOPE 0.01f
#define BN_EPS 1e-5f
#define CHUNK 2048
#define KMAX 27
#define PIMASK 0xFFFFFF

// ---------------- CSR build ----------------

__global__ void __launch_bounds__(256) hist_kernel(
    const int* __restrict__ po, int* __restrict__ cnt, int E)
{
    int i = blockIdx.x * blockDim.x + threadIdx.x;
    if (i < E) atomicAdd(&cnt[po[i]], 1);
}

__global__ void __launch_bounds__(256) blocksum_kernel(
    const int* __restrict__ cnt, int* __restrict__ bsum, int N)
{
    int base = blockIdx.x * CHUNK + threadIdx.x * 8;
    int s = 0;
#pragma unroll
    for (int j = 0; j < 8; ++j) { int i = base + j; if (i < N) s += cnt[i]; }
#pragma unroll
    for (int off = 1; off < 64; off <<= 1) s += __shfl_xor(s, off);
    __shared__ int wsum[4];
    if ((threadIdx.x & 63) == 0) wsum[threadIdx.x >> 6] = s;
    __syncthreads();
    if (threadIdx.x == 0) bsum[blockIdx.x] = wsum[0] + wsum[1] + wsum[2] + wsum[3];
}

// parallel exclusive scan of up to 1024 block sums, one block of 256 threads
__global__ void __launch_bounds__(256) scanblk_kernel(
    const int* __restrict__ bsum, int* __restrict__ boffs, int nb)
{
    __shared__ int ts[256];
    int tid = threadIdx.x;
    int v[4]; int s = 0;
#pragma unroll
    for (int j = 0; j < 4; ++j) {
        int i = tid * 4 + j;
        v[j] = (i < nb) ? bsum[i] : 0;
        s += v[j];
    }
    ts[tid] = s;
    __syncthreads();
    // Hillis-Steele inclusive scan on ts
    for (int off = 1; off < 256; off <<= 1) {
        int add = (tid >= off) ? ts[tid - off] : 0;
        __syncthreads();
        ts[tid] += add;
        __syncthreads();
    }
    int run = ts[tid] - s;   // exclusive prefix of this thread's chunk
#pragma unroll
    for (int j = 0; j < 4; ++j) {
        int i = tid * 4 + j;
        if (i < nb) { boffs[i] = run; run += v[j]; }
    }
}

__global__ void __launch_bounds__(256) scatteroffs_kernel(
    int* __restrict__ cnt, int* __restrict__ cursors,
    const int* __restrict__ boffs, int N)
{
    int tid = threadIdx.x;
    int base = blockIdx.x * CHUNK + tid * 8;
    int c[8]; int tsum = 0;
#pragma unroll
    for (int j = 0; j < 8; ++j) { int i = base + j; c[j] = (i < N) ? cnt[i] : 0; tsum += c[j]; }
    __shared__ int lts[256];
    lts[tid] = tsum;
    __syncthreads();
    int off = boffs[blockIdx.x];
    for (int j = 0; j < tid; ++j) off += lts[j];
#pragma unroll
    for (int j = 0; j < 8; ++j) {
        int i = base + j;
        if (i < N) { cnt[i] = off; cursors[i] = off; off += c[j]; }
    }
}

// store (k<<24)|pi so the fused kernel needs no pairs_in indirection
__global__ void __launch_bounds__(256) scatter_kernel(
    const int* __restrict__ pairs_out, const int* __restrict__ pairs_in,
    int* __restrict__ cursors, int* __restrict__ sorted, int P)
{
    int p = blockIdx.x * blockDim.x + threadIdx.x;
    int k = blockIdx.y;
    if (p >= P) return;
    int po = pairs_out[(size_t)k * P + p];
    int pi = pairs_in[(size_t)k * P + p];
    int slot = atomicAdd(&cursors[po], 1);
    sorted[slot] = (k << 24) | pi;
}

// ---------------- row balancing: counting-sort rows by entry count ----------------

__global__ void __launch_bounds__(256) binhist_kernel(
    const int* __restrict__ offsets, int* __restrict__ binCnt, int N, int E)
{
    __shared__ int lb[64];
    int tid = threadIdx.x;
    if (tid < 64) lb[tid] = 0;
    __syncthreads();
    int r = blockIdx.x * 256 + tid;
    if (r < N) {
        int beg = offsets[r];
        int end = (r == N - 1) ? E : offsets[r + 1];
        int c = end - beg; if (c > 63) c = 63;
        atomicAdd(&lb[c], 1);
    }
    __syncthreads();
    if (tid < 64 && lb[tid] > 0) atomicAdd(&binCnt[tid * 8], lb[tid]);
}

__global__ void binscan_kernel(const int* __restrict__ binCnt, int* __restrict__ binCur)
{
    int tid = threadIdx.x;           // 64 threads
    int v = binCnt[tid * 8];
    int x = v;
#pragma unroll
    for (int off = 1; off < 64; off <<= 1) {
        int y = __shfl_up(x, off);
        if (tid >= off) x += y;
    }
    binCur[tid * 8] = x - v;         // exclusive
}

__global__ void __launch_bounds__(256) rowscatter_kernel(
    const int* __restrict__ offsets, int* __restrict__ binCur,
    int* __restrict__ rowperm, int N, int E)
{
    __shared__ int lb[64];
    __shared__ int lbase[64];
    int tid = threadIdx.x;
    if (tid < 64) lb[tid] = 0;
    __syncthreads();
    int r = blockIdx.x * 256 + tid;
    int c = -1, my = 0;
    if (r < N) {
        int beg = offsets[r];
        int end = (r == N - 1) ? E : offsets[r + 1];
        c = end - beg; if (c > 63) c = 63;
        my = atomicAdd(&lb[c], 1);
    }
    __syncthreads();
    if (tid < 64 && lb[tid] > 0) lbase[tid] = atomicAdd(&binCur[tid * 8], lb[tid]);
    __syncthreads();
    if (r < N) rowperm[lbase[c] + my] = r;
}

// ---------------- fused conv + lrelu + stats ----------------
// thread = one output row (via rowperm); W (27x32x32) in LDS as f16

__global__ void __launch_bounds__(256, 2) fused_conv_kernel(
    const float* __restrict__ features,
    const float* __restrict__ weight,
    const int* __restrict__ sorted,
    const int* __restrict__ offsets,
    const int* __restrict__ rowperm,
    float* __restrict__ out,
    float* __restrict__ gstats,         // [0..31] sum, [32..63] sumsq
    int N, int E)
{
    __shared__ uint4 wlds[32 * 4 * KMAX];        // 55,296 B
    __shared__ float sred[4][32];
    __shared__ float qred[4][32];

    // stage W: global fp32 [k][c][co] -> LDS f16 chunk[((c*4)+(co>>3))*27+k][co&7]
    {
        __half* hl = (__half*)wlds;
        for (int s = threadIdx.x; s < KMAX * 1024; s += 256) {
            int k = s >> 10;
            int rem = s & 1023;
            int c = rem >> 5;
            int co = rem & 31;
            float v = weight[s];
            int dst = (((c << 2) + (co >> 3)) * KMAX + k) * 8 + (co & 7);
            hl[dst] = __float2half(v);
        }
    }
    __syncthreads();

    int gid = blockIdx.x * 256 + threadIdx.x;
    int r = (gid < N) ? rowperm[gid] : -1;

    float acc[COUT];
#pragma unroll
    for (int co = 0; co < COUT; ++co) acc[co] = 0.f;

    if (r >= 0) {
        int beg = offsets[r];
        int end = (r == N - 1) ? E : offsets[r + 1];
        int cnt = end - beg;
        if (cnt > 0) {
            int pk0 = sorted[beg];
            float4 fc[8];
            {
                const float4* fr = (const float4*)(features + (size_t)(pk0 & PIMASK) * CIN);
#pragma unroll
                for (int i = 0; i < 8; ++i) fc[i] = fr[i];
            }
            for (int e = 0; e < cnt; ++e) {
                int pk1 = (beg + e + 1 < end) ? sorted[beg + e + 1] : pk0;
                float4 fn[8];
                {
                    const float4* fr = (const float4*)(features + (size_t)(pk1 & PIMASK) * CIN);
#pragma unroll
                    for (int i = 0; i < 8; ++i) fn[i] = fr[i];
                }
                int k = pk0 >> 24;
#pragma unroll
                for (int c4 = 0; c4 < 8; ++c4) {
                    float4 fq = fc[c4];
                    float fv[4] = {fq.x, fq.y, fq.z, fq.w};
#pragma unroll
                    for (int j = 0; j < 4; ++j) {
                        int c = c4 * 4 + j;
                        float f = fv[j];
#pragma unroll
                        for (int co8 = 0; co8 < 4; ++co8) {
                            uint4 w = wlds[((c << 2) + co8) * KMAX + k];
                            const __half2* h2 = reinterpret_cast<const __half2*>(&w);
                            int b = co8 * 8;
                            acc[b + 0] = fmaf(f, __low2float(h2[0]),  acc[b + 0]);
                            acc[b + 1] = fmaf(f, __high2float(h2[0]), acc[b + 1]);
                            acc[b + 2] = fmaf(f, __low2float(h2[1]),  acc[b + 2]);
                            acc[b + 3] = fmaf(f, __high2float(h2[1]), acc[b + 3]);
                            acc[b + 4] = fmaf(f, __low2float(h2[2]),  acc[b + 4]);
                            acc[b + 5] = fmaf(f, __high2float(h2[2]), acc[b + 5]);
                            acc[b + 6] = fmaf(f, __low2float(h2[3]),  acc[b + 6]);
                            acc[b + 7] = fmaf(f, __high2float(h2[3]), acc[b + 7]);
                        }
                    }
                }
                pk0 = pk1;
#pragma unroll
                for (int i = 0; i < 8; ++i) fc[i] = fn[i];
            }
        }
    }

    // LeakyReLU + store
    float act[COUT];
#pragma unroll
    for (int co = 0; co < COUT; ++co) {
        float a = acc[co];
        act[co] = a >= 0.f ? a : LRELU_SLOPE * a;
    }
    if (r >= 0) {
        float4* orow = (float4*)(out + (size_t)r * COUT);
#pragma unroll
        for (int i = 0; i < 8; ++i)
            orow[i] = make_float4(act[i * 4], act[i * 4 + 1], act[i * 4 + 2], act[i * 4 + 3]);
    }

    // stats
    float q[COUT];
#pragma unroll
    for (int co = 0; co < COUT; ++co) q[co] = act[co] * act[co];
#pragma unroll
    for (int off = 1; off < 64; off <<= 1) {
#pragma unroll
        for (int co = 0; co < COUT; ++co) {
            act[co] += __shfl_xor(act[co], off);
            q[co]   += __shfl_xor(q[co], off);
        }
    }
    int lane = threadIdx.x & 63;
    int wv = threadIdx.x >> 6;
    if (lane == 0) {
#pragma unroll
        for (int co = 0; co < COUT; ++co) { sred[wv][co] = act[co]; qred[wv][co] = q[co]; }
    }
    __syncthreads();
    if (threadIdx.x < 32) {
        int c = threadIdx.x;
        float S = sred[0][c] + sred[1][c] + sred[2][c] + sred[3][c];
        float Q = qred[0][c] + qred[1][c] + qred[2][c] + qred[3][c];
        atomicAdd(&gstats[c], S);
        atomicAdd(&gstats[32 + c], Q);
    }
}

// norm WITHOUT re-applying lrelu
__global__ void __launch_bounds__(256) norm2_kernel(
    float* __restrict__ data, const float* __restrict__ stats,
    const float* __restrict__ gamma, const float* __restrict__ beta,
    int n4, float invN)
{
    int i = blockIdx.x * blockDim.x + threadIdx.x;
    if (i >= n4) return;
    int qd = i & 7;
    float sc[4], bs[4];
#pragma unroll
    for (int j = 0; j < 4; ++j) {
        int c = qd * 4 + j;
        float m = stats[c] * invN;
        float v = stats[32 + c] * invN - m * m;
        float inv = rsqrtf(v + BN_EPS);
        sc[j] = inv * gamma[c];
        bs[j] = beta[c] - m * sc[j];
    }
    float4* d4 = (float4*)data;
    float4 a = d4[i];
    float4 y;
    y.x = a.x * sc[0] + bs[0];
    y.y = a.y * sc[1] + bs[1];
    y.z = a.z * sc[2] + bs[2];
    y.w = a.w * sc[3] + bs[3];
    d4[i] = y;
}

// ---------------- fallback path (atomic version) ----------------

__global__ void __launch_bounds__(256) conv_atomic_kernel(
    const float* __restrict__ features,
    const float* __restrict__ weight,
    const int* __restrict__ pairs_in,
    const int* __restrict__ pairs_out,
    float* __restrict__ out,
    int P)
{
    int p = blockIdx.x * blockDim.x + threadIdx.x;
    int k = blockIdx.y;
    if (p >= P) return;
    int pi = pairs_in[(size_t)k * P + p];
    int po = pairs_out[(size_t)k * P + p];
    const float4* __restrict__ frow = (const float4*)(features + (size_t)pi * CIN);
    const float* __restrict__ wk = weight + (size_t)k * CIN * COUT;
    float acc[COUT];
#pragma unroll
    for (int co = 0; co < COUT; ++co) acc[co] = 0.f;
#pragma unroll
    for (int c4 = 0; c4 < CIN / 4; ++c4) {
        float4 f = frow[c4];
        float fv[4] = {f.x, f.y, f.z, f.w};
#pragma unroll
        for (int j = 0; j < 4; ++j) {
            const float* __restrict__ wr = wk + (c4 * 4 + j) * COUT;
#pragma unroll
            for (int co = 0; co < COUT; ++co)
                acc[co] = fmaf(fv[j], wr[co], acc[co]);
        }
    }
    float* orow = out + (size_t)po * COUT;
#pragma unroll
    for (int co = 0; co < COUT; ++co)
        atomicAdd(orow + co, acc[co]);
}

__device__ __forceinline__ float4 lrelu4(float4 v) {
    float4 a;
    a.x = v.x >= 0.f ? v.x : LRELU_SLOPE * v.x;
    a.y = v.y >= 0.f ? v.y : LRELU_SLOPE * v.y;
    a.z = v.z >= 0.f ? v.z : LRELU_SLOPE * v.z;
    a.w = v.w >= 0.f ? v.w : LRELU_SLOPE * v.w;
    return a;
}

__global__ void __launch_bounds__(256) stats_fb_kernel(
    const float* __restrict__ conv, float* __restrict__ stats, int n4)
{
    const float4* __restrict__ c4p = (const float4*)conv;
    int stride = blockDim.x * gridDim.x;
    float4 s = {0.f, 0.f, 0.f, 0.f};
    float4 q = {0.f, 0.f, 0.f, 0.f};
    for (int i = blockIdx.x * blockDim.x + threadIdx.x; i < n4; i += stride) {
        float4 a = lrelu4(c4p[i]);
        s.x += a.x; s.y += a.y; s.z += a.z; s.w += a.w;
        q.x += a.x * a.x; q.y += a.y * a.y; q.z += a.z * a.z; q.w += a.w * a.w;
    }
#pragma unroll
    for (int off = 8; off < 64; off <<= 1) {
        s.x += __shfl_xor(s.x, off); s.y += __shfl_xor(s.y, off);
        s.z += __shfl_xor(s.z, off); s.w += __shfl_xor(s.w, off);
        q.x += __shfl_xor(q.x, off); q.y += __shfl_xor(q.y, off);
        q.z += __shfl_xor(q.z, off); q.w += __shfl_xor(q.w, off);
    }
    __shared__ float4 rs[4][8];
    __shared__ float4 rq[4][8];
    int lane = threadIdx.x & 63;
    int w = threadIdx.x >> 6;
    if (lane < 8) { rs[w][lane] = s; rq[w][lane] = q; }
    __syncthreads();
    if (threadIdx.x < 8) {
        int qd = threadIdx.x;
        float4 S = {0.f, 0.f, 0.f, 0.f};
        float4 Q = {0.f, 0.f, 0.f, 0.f};
        for (int ww = 0; ww < 4; ++ww) {
            float4 a = rs[ww][qd], b = rq[ww][qd];
            S.x += a.x; S.y += a.y; S.z += a.z; S.w += a.w;
            Q.x += b.x; Q.y += b.y; Q.z += b.z; Q.w += b.w;
        }
        atomicAdd(&stats[qd * 4 + 0], S.x); atomicAdd(&stats[qd * 4 + 1], S.y);
        atomicAdd(&stats[qd * 4 + 2], S.z); atomicAdd(&stats[qd * 4 + 3], S.w);
        atomicAdd(&stats[32 + qd * 4 + 0], Q.x); atomicAdd(&stats[32 + qd * 4 + 1], Q.y);
        atomicAdd(&stats[32 + qd * 4 + 2], Q.z); atomicAdd(&stats[32 + qd * 4 + 3], Q.w);
    }
}

__global__ void __launch_bounds__(256) norm_fb_kernel(
    float* __restrict__ data, const float* __restrict__ stats,
    const float* __restrict__ gamma, const float* __restrict__ beta,
    int n4, float invN)
{
    int i = blockIdx.x * blockDim.x + threadIdx.x;
    if (i >= n4) return;
    int qd = i & 7;
    float sc[4], bs[4];
#pragma unroll
    for (int j = 0; j < 4; ++j) {
        int c = qd * 4 + j;
        float m = stats[c] * invN;
        float v = stats[32 + c] * invN - m * m;
        float inv = rsqrtf(v + BN_EPS);
        sc[j] = inv * gamma[c];
        bs[j] = beta[c] - m * sc[j];
    }
    float4* d4 = (float4*)data;
    float4 a = lrelu4(d4[i]);
    float4 y;
    y.x = a.x * sc[0] + bs[0];
    y.y = a.y * sc[1] + bs[1];
    y.z = a.z * sc[2] + bs[2];
    y.w = a.w * sc[3] + bs[3];
    d4[i] = y;
}

extern "C" void kernel_launch(void* const* d_in, const int* in_sizes, int n_in,
                              void* d_out, int out_size, void* d_ws, size_t ws_size,
                              hipStream_t stream) {
    const float* features = (const float*)d_in[0];
    const float* weight   = (const float*)d_in[1];
    const float* gamma    = (const float*)d_in[2];
    const float* beta     = (const float*)d_in[3];
    const int* pairs_in   = (const int*)d_in[4];
    const int* pairs_out  = (const int*)d_in[5];
    float* out = (float*)d_out;

    int N  = in_sizes[0] / CIN;           // 500000
    int KW = in_sizes[1] / (CIN * COUT);  // 27
    int P  = in_sizes[4] / KW;            // 250000
    int E  = KW * P;                      // 6,750,000
    int n4 = N * (COUT / 4);

    // ws layout: stats | offsets[N] | cursors[N](-> reused as rowperm) | bsum[1024]
    //            | boffs[1024] | binCnt[512] | binCur[512] | sorted[E]
    char* wsb = (char*)d_ws;
    float* stats  = (float*)wsb;                          // 64 floats (256 B slot)
    int* offsets  = (int*)(wsb + 256);
    int* cursors  = offsets + N;                          // later: rowperm
    int* bsum     = cursors + N;
    int* boffs    = bsum + 1024;
    int* binCnt   = boffs + 1024;
    int* binCur   = binCnt + 512;
    int* sorted   = binCur + 512;
    size_t need = 256 + (size_t)(2 * N + 3072 + E) * 4;

    bool fast = (ws_size >= need) && (KW <= KMAX) && (N <= (1 << 24));

    if (fast) {
        hipMemsetAsync(stats, 0, 256, stream);
        hipMemsetAsync(offsets, 0, (size_t)N * sizeof(int), stream);
        hipMemsetAsync(binCnt, 0, 512 * sizeof(int), stream);

        hist_kernel<<<(E + 255) / 256, 256, 0, stream>>>(pairs_out, offsets, E);

        int nb = (N + CHUNK - 1) / CHUNK;
        blocksum_kernel<<<nb, 256, 0, stream>>>(offsets, bsum, N);
        scanblk_kernel<<<1, 256, 0, stream>>>(bsum, boffs, nb);
        scatteroffs_kernel<<<nb, 256, 0, stream>>>(offsets, cursors, boffs, N);

        dim3 sgrid((P + 255) / 256, KW);
        scatter_kernel<<<sgrid, 256, 0, stream>>>(pairs_out, pairs_in, cursors, sorted, P);

        int nrb = (N + 255) / 256;
        binhist_kernel<<<nrb, 256, 0, stream>>>(offsets, binCnt, N, E);
        binscan_kernel<<<1, 64, 0, stream>>>(binCnt, binCur);
        int* rowperm = cursors;   // reuse
        rowscatter_kernel<<<nrb, 256, 0, stream>>>(offsets, binCur, rowperm, N, E);

        fused_conv_kernel<<<nrb, 256, 0, stream>>>(
            features, weight, sorted, offsets, rowperm, out, stats, N, E);

        norm2_kernel<<<(n4 + 255) / 256, 256, 0, stream>>>(out, stats, gamma, beta,
                                                           n4, 1.0f / (float)N);
    } else {
        hipMemsetAsync(d_out, 0, (size_t)out_size * sizeof(float), stream);
        hipMemsetAsync(d_ws, 0, 64 * sizeof(float), stream);
        dim3 cgrid((P + 255) / 256, KW);
        conv_atomic_kernel<<<cgrid, 256, 0, stream>>>(features, weight, pairs_in,
                                                      pairs_out, (float*)d_out, P);
        stats_fb_kernel<<<512, 256, 0, stream>>>((const float*)d_out, (float*)d_ws, n4);
        norm_fb_kernel<<<(n4 + 255) / 256, 256, 0, stream>>>((float*)d_out, (float*)d_ws,
                                                             gamma, beta, n4,
                                                             1.0f / (float)N);
    }
}